// Round 3
// baseline (591.335 us; speedup 1.0000x reference)
//
#include <hip/hip_runtime.h>
#include <cstdint>
#include <cstddef>

typedef __bf16 bf16;
typedef __bf16 bf16x8 __attribute__((ext_vector_type(8)));
typedef float  f32x4  __attribute__((ext_vector_type(4)));
typedef unsigned short u16;

#define NEG_SCORE -1.0e10f
#define MD ((size_t)8388608)   // 16384*512 elements

// =====================================================================
// dtype probe: decide whether float inputs are fp32 or bf16 on device.
// Reads first 16384 uint16 halves of X. bf16 N(0,1) data: every half is a
// genuine bf16, exponent <= ~130. fp32 data: low halves are mantissa bits
// (uniform random) -> ~45%/half chance of exponent >= 141. flag=1 -> fp32.
// =====================================================================
__global__ __launch_bounds__(256)
void probe_dtype(const u16* __restrict__ x, int* __restrict__ flag)
{
  __shared__ int bad;
  if (threadIdx.x == 0) bad = 0;
  __syncthreads();
  int my = 0;
  for (int i = threadIdx.x; i < 16384; i += 256) {
    const int e = (x[i] >> 7) & 0xFF;   // bf16 exponent field
    if (e >= 141) my = 1;               // |v| >= 2^14 (or Inf/NaN)
  }
  if (my) atomicOr(&bad, 1);
  __syncthreads();
  if (threadIdx.x == 0) *flag = bad;
}

// =====================================================================
// Batched conversion of all 20 float tensors into bf16 staging in ws.
// Per the flag: fp32 -> cvt to bf16, else bf16 -> copy. 2048 elems/block.
// =====================================================================
struct ConvSrc { const void* p[20]; };

__global__ __launch_bounds__(256)
void convert_all(ConvSrc s, bf16* __restrict__ ws, const int* __restrict__ flag)
{
  const int n[20] = {8388608, 8388608,
                     262144, 262144, 262144, 262144, 262144, 262144, 262144, 262144,
                     1048576, 2048, 1048576, 512, 512, 512, 512, 512, 512, 512};
  const unsigned int doff[20] = {
      41943040u, 50331648u,
      58720256u, 58982400u, 59244544u, 59506688u,
      59768832u, 60030976u, 60293120u, 60555264u,
      60817408u, 61865984u, 61868032u, 62916608u,
      62917120u, 62917632u, 62918144u, 62918656u, 62919168u, 62919680u};

  int bi = blockIdx.x;
  int idx = 0, b0 = 0;
  for (; idx < 20; ++idx) {
    const int nb = (n[idx] + 2047) >> 11;
    if (bi < b0 + nb) break;
    b0 += nb;
  }
  const int i = ((bi - b0) << 11) + threadIdx.x * 8;
  if (i >= n[idx]) return;
  bf16* dst = ws + doff[idx] + i;
  if (*flag) {
    const float* sp = (const float*)s.p[idx] + i;
    f32x4 a = *(const f32x4*)sp;
    f32x4 b = *(const f32x4*)(sp + 4);
    bf16x8 o;
#pragma unroll
    for (int e = 0; e < 4; ++e) { o[e] = (bf16)a[e]; o[4 + e] = (bf16)b[e]; }
    *(bf16x8*)dst = o;
  } else {
    *(bf16x8*)dst = *(const bf16x8*)((const bf16*)s.p[idx] + i);
  }
}

// =====================================================================
// GEMM: C[M,N] = act(A[M,K] @ B[N,K]^T + bias), bf16 in, fp32 accum.
// MODE 0: plain, MODE 1: bias + LeakyReLU(0.01), MODE 2: bias only.
// 128x128 tile, BK=32, 4 waves (2x2 of 64x64), mfma_f32_16x16x32_bf16.
// =====================================================================
template<int MODE>
__global__ __launch_bounds__(256)
void gemm_bt(const bf16* __restrict__ A, const bf16* __restrict__ B,
             const bf16* __restrict__ bias, bf16* __restrict__ C,
             int M, int N, int K)
{
  __shared__ __attribute__((aligned(16))) bf16 As[128 * 32];
  __shared__ __attribute__((aligned(16))) bf16 Bs[128 * 32];

  const int t    = threadIdx.x;
  const int wave = t >> 6;
  const int lane = t & 63;
  const int quad = lane >> 4;
  const int l15  = lane & 15;
  const int wr   = (wave >> 1) * 64;
  const int wc   = (wave & 1) * 64;
  const int m0   = blockIdx.y * 128;
  const int n0   = blockIdx.x * 128;

  const int row0 = t >> 2;             // 0..63
  const int kg0  = (t & 3) << 3;       // 0,8,16,24

  const f32x4 fz = {0.f, 0.f, 0.f, 0.f};
  f32x4 acc[4][4];
#pragma unroll
  for (int i = 0; i < 4; ++i)
#pragma unroll
    for (int j = 0; j < 4; ++j) acc[i][j] = fz;

  const int nkt = K >> 5;
  for (int kt = 0; kt < nkt; ++kt) {
    const int k0 = kt << 5;
    bf16x8 a0 = *(const bf16x8*)(A + (size_t)(m0 + row0)      * K + k0 + kg0);
    bf16x8 a1 = *(const bf16x8*)(A + (size_t)(m0 + row0 + 64) * K + k0 + kg0);
    bf16x8 b0 = *(const bf16x8*)(B + (size_t)(n0 + row0)      * K + k0 + kg0);
    bf16x8 b1 = *(const bf16x8*)(B + (size_t)(n0 + row0 + 64) * K + k0 + kg0);
    __syncthreads();
    *(bf16x8*)(As + (size_t)t * 8)         = a0;
    *(bf16x8*)(As + (size_t)(t + 256) * 8) = a1;
    *(bf16x8*)(Bs + (size_t)t * 8)         = b0;
    *(bf16x8*)(Bs + (size_t)(t + 256) * 8) = b1;
    __syncthreads();

    bf16x8 af[4], bfv[4];
#pragma unroll
    for (int i = 0; i < 4; ++i)
      af[i] = *(const bf16x8*)(As + (wr + i * 16 + l15) * 32 + quad * 8);
#pragma unroll
    for (int j = 0; j < 4; ++j)
      bfv[j] = *(const bf16x8*)(Bs + (wc + j * 16 + l15) * 32 + quad * 8);
#pragma unroll
    for (int i = 0; i < 4; ++i)
#pragma unroll
      for (int j = 0; j < 4; ++j)
        acc[i][j] = __builtin_amdgcn_mfma_f32_16x16x32_bf16(af[i], bfv[j],
                                                            acc[i][j], 0, 0, 0);
  }

#pragma unroll
  for (int i = 0; i < 4; ++i) {
    const int m = m0 + wr + i * 16 + quad * 4;
#pragma unroll
    for (int j = 0; j < 4; ++j) {
      const int n = n0 + wc + j * 16 + l15;
      float bv = 0.f;
      if (MODE >= 1) bv = (float)bias[n];
#pragma unroll
      for (int r = 0; r < 4; ++r) {
        float v = acc[i][j][r];
        if (MODE >= 1) v += bv;
        if (MODE == 1) v = v > 0.f ? v : 0.01f * v;
        C[(size_t)(m + r) * N + n] = (bf16)v;
      }
    }
  }
}

// =====================================================================
// Flash attention. One block = (b, h, 64 queries); 4 waves x 16 q-rows.
// O may alias Q (each block reads exactly the Q slice it writes as O).
// =====================================================================
#define ATT_T 512
#define ATT_D 512

__global__ __launch_bounds__(256)
void flash_attn(const bf16* Q, const bf16* __restrict__ Kg,
                const bf16* __restrict__ Vg, bf16* O,
                const int* __restrict__ vlen, int per_query)
{
  __shared__ __attribute__((aligned(16))) bf16 Qs[64][72];
  __shared__ __attribute__((aligned(16))) bf16 Ks[64][72];
  __shared__ __attribute__((aligned(16))) bf16 VsT[64][72];
  __shared__ __attribute__((aligned(16))) bf16 Ps[4][16][72];
  __shared__ int vlmax_sh;

  const int t    = threadIdx.x;
  const int wave = t >> 6;
  const int lane = t & 63;
  const int quad = lane >> 4;
  const int l15  = lane & 15;
  const int bx   = blockIdx.x;
  const int qt   = bx & 7;
  const int h    = (bx >> 3) & 7;
  const int b    = bx >> 6;

  if (t == 0) vlmax_sh = 1;

  {
    const int r  = t >> 2;
    const int d0 = (t & 3) << 4;
    const bf16* gq = Q + (size_t)(b * ATT_T + qt * 64 + r) * ATT_D + h * 64 + d0;
    *(bf16x8*)&Qs[r][d0]     = *(const bf16x8*)gq;
    *(bf16x8*)&Qs[r][d0 + 8] = *(const bf16x8*)(gq + 8);
  }
  __syncthreads();
  if (t < 64) {
    int q = qt * 64 + t;
    int v = per_query ? vlen[b * ATT_T + q] : vlen[b];
    atomicMax(&vlmax_sh, v);
  }

  int vl_r[4];
#pragma unroll
  for (int r = 0; r < 4; ++r) {
    int q = qt * 64 + wave * 16 + quad * 4 + r;
    vl_r[r] = per_query ? vlen[b * ATT_T + q] : vlen[b];
  }

  const f32x4 fz = {0.f, 0.f, 0.f, 0.f};
  float m_run[4] = {-1e30f, -1e30f, -1e30f, -1e30f};
  float l_run[4] = {0.f, 0.f, 0.f, 0.f};
  f32x4 o_acc[4] = {fz, fz, fz, fz};

  __syncthreads();
  const int ktiles = (vlmax_sh + 63) >> 6;

  for (int kt = 0; kt < ktiles; ++kt) {
    const int k0 = kt * 64;
    __syncthreads();
    {
      const int r  = t >> 2;
      const int d0 = (t & 3) << 4;
      const bf16* gk = Kg + (size_t)(b * ATT_T + k0 + r) * ATT_D + h * 64 + d0;
      *(bf16x8*)&Ks[r][d0]     = *(const bf16x8*)gk;
      *(bf16x8*)&Ks[r][d0 + 8] = *(const bf16x8*)(gk + 8);
      const bf16* gv = Vg + (size_t)(b * ATT_T + k0 + r) * ATT_D + h * 64 + d0;
      bf16x8 v0 = *(const bf16x8*)gv;
      bf16x8 v1 = *(const bf16x8*)(gv + 8);
#pragma unroll
      for (int e = 0; e < 8; ++e) {
        VsT[d0 + e][r]     = v0[e];
        VsT[d0 + 8 + e][r] = v1[e];
      }
    }
    __syncthreads();

    f32x4 s[4] = {fz, fz, fz, fz};
#pragma unroll
    for (int ks = 0; ks < 2; ++ks) {
      bf16x8 aq = *(const bf16x8*)&Qs[wave * 16 + l15][ks * 32 + quad * 8];
#pragma unroll
      for (int nt = 0; nt < 4; ++nt) {
        bf16x8 bk = *(const bf16x8*)&Ks[nt * 16 + l15][ks * 32 + quad * 8];
        s[nt] = __builtin_amdgcn_mfma_f32_16x16x32_bf16(aq, bk, s[nt], 0, 0, 0);
      }
    }

    float sv[4][4];
#pragma unroll
    for (int nt = 0; nt < 4; ++nt) {
      const int k_abs = k0 + nt * 16 + l15;
#pragma unroll
      for (int r = 0; r < 4; ++r) {
        float v = s[nt][r] * 0.125f;
        sv[nt][r] = (k_abs < vl_r[r]) ? v : NEG_SCORE;
      }
    }

    float alpha[4];
#pragma unroll
    for (int r = 0; r < 4; ++r) {
      float v = fmaxf(fmaxf(sv[0][r], sv[1][r]), fmaxf(sv[2][r], sv[3][r]));
#pragma unroll
      for (int off = 1; off < 16; off <<= 1)
        v = fmaxf(v, __shfl_xor(v, off));
      const float m_new = fmaxf(m_run[r], v);
      alpha[r] = __expf(m_run[r] - m_new);
      m_run[r] = m_new;
    }
#pragma unroll
    for (int r = 0; r < 4; ++r) {
      float sum = 0.f;
#pragma unroll
      for (int nt = 0; nt < 4; ++nt) {
        float p = __expf(sv[nt][r] - m_run[r]);
        sv[nt][r] = p;
        sum += p;
      }
#pragma unroll
      for (int off = 1; off < 16; off <<= 1)
        sum += __shfl_xor(sum, off);
      l_run[r] = alpha[r] * l_run[r] + sum;
    }

#pragma unroll
    for (int nt = 0; nt < 4; ++nt) {
#pragma unroll
      for (int r = 0; r < 4; ++r)
        Ps[wave][quad * 4 + r][nt * 16 + l15] = (bf16)sv[nt][r];
      o_acc[nt][0] *= alpha[0];
      o_acc[nt][1] *= alpha[1];
      o_acc[nt][2] *= alpha[2];
      o_acc[nt][3] *= alpha[3];
    }
    __syncthreads();

#pragma unroll
    for (int ks = 0; ks < 2; ++ks) {
      bf16x8 ap = *(const bf16x8*)&Ps[wave][l15][ks * 32 + quad * 8];
#pragma unroll
      for (int nt = 0; nt < 4; ++nt) {
        bf16x8 bv = *(const bf16x8*)&VsT[nt * 16 + l15][ks * 32 + quad * 8];
        o_acc[nt] = __builtin_amdgcn_mfma_f32_16x16x32_bf16(ap, bv, o_acc[nt], 0, 0, 0);
      }
    }
  }

#pragma unroll
  for (int r = 0; r < 4; ++r) {
    const int q = qt * 64 + wave * 16 + quad * 4 + r;
    const float inv_l = (l_run[r] > 0.f) ? (1.f / l_run[r]) : 0.f;
#pragma unroll
    for (int nt = 0; nt < 4; ++nt) {
      const int d = nt * 16 + l15;
      O[(size_t)(b * ATT_T + q) * ATT_D + h * 64 + d] = (bf16)(o_acc[nt][r] * inv_l);
    }
  }
}

// =====================================================================
// AddNorm (internal, bf16 out). One wave per 512-row. In-place safe.
// =====================================================================
__global__ __launch_bounds__(256)
void add_layernorm(const bf16* X, const bf16* R,
                   const bf16* __restrict__ gamma, const bf16* __restrict__ beta,
                   bf16* Out)
{
  const int t    = threadIdx.x;
  const int wave = t >> 6;
  const int lane = t & 63;
  const size_t row  = (size_t)blockIdx.x * 4 + wave;
  const size_t base = row * 512 + lane * 8;

  bf16x8 xv = *(const bf16x8*)(X + base);
  bf16x8 rv = *(const bf16x8*)(R + base);
  float v[8];
  float sum = 0.f, ss = 0.f;
#pragma unroll
  for (int i = 0; i < 8; ++i) {
    v[i] = (float)xv[i] + (float)rv[i];
    sum += v[i];
    ss  += v[i] * v[i];
  }
#pragma unroll
  for (int off = 1; off < 64; off <<= 1) {
    sum += __shfl_xor(sum, off);
    ss  += __shfl_xor(ss, off);
  }
  const float mean = sum * (1.f / 512.f);
  const float var  = ss * (1.f / 512.f) - mean * mean;
  const float rstd = rsqrtf(var + 1e-5f);

  bf16x8 gv = *(const bf16x8*)(gamma + lane * 8);
  bf16x8 bv = *(const bf16x8*)(beta + lane * 8);
  bf16x8 ov;
#pragma unroll
  for (int i = 0; i < 8; ++i)
    ov[i] = (bf16)(((v[i] - mean) * rstd) * (float)gv[i] + (float)bv[i]);
  *(bf16x8*)(Out + base) = ov;
}

// =====================================================================
// Final AddNorm: writes d_out as fp32 or bf16 per the dtype flag.
// =====================================================================
__global__ __launch_bounds__(256)
void add_layernorm_out(const bf16* X, const bf16* R,
                       const bf16* __restrict__ gamma, const bf16* __restrict__ beta,
                       void* Out, const int* __restrict__ flag)
{
  const int t    = threadIdx.x;
  const int wave = t >> 6;
  const int lane = t & 63;
  const size_t row  = (size_t)blockIdx.x * 4 + wave;
  const size_t base = row * 512 + lane * 8;

  bf16x8 xv = *(const bf16x8*)(X + base);
  bf16x8 rv = *(const bf16x8*)(R + base);
  float v[8];
  float sum = 0.f, ss = 0.f;
#pragma unroll
  for (int i = 0; i < 8; ++i) {
    v[i] = (float)xv[i] + (float)rv[i];
    sum += v[i];
    ss  += v[i] * v[i];
  }
#pragma unroll
  for (int off = 1; off < 64; off <<= 1) {
    sum += __shfl_xor(sum, off);
    ss  += __shfl_xor(ss, off);
  }
  const float mean = sum * (1.f / 512.f);
  const float var  = ss * (1.f / 512.f) - mean * mean;
  const float rstd = rsqrtf(var + 1e-5f);

  bf16x8 gv = *(const bf16x8*)(gamma + lane * 8);
  bf16x8 bv = *(const bf16x8*)(beta + lane * 8);
  float o[8];
#pragma unroll
  for (int i = 0; i < 8; ++i)
    o[i] = ((v[i] - mean) * rstd) * (float)gv[i] + (float)bv[i];

  if (*flag) {
    float* op = (float*)Out + base;
    f32x4 o0 = {o[0], o[1], o[2], o[3]};
    f32x4 o1 = {o[4], o[5], o[6], o[7]};
    *(f32x4*)op       = o0;
    *(f32x4*)(op + 4) = o1;
  } else {
    bf16x8 ov;
#pragma unroll
    for (int i = 0; i < 8; ++i) ov[i] = (bf16)o[i];
    *(bf16x8*)((bf16*)Out + base) = ov;
  }
}

// =====================================================================
extern "C" void kernel_launch(void* const* d_in, const int* in_sizes, int n_in,
                              void* d_out, int out_size, void* d_ws, size_t ws_size,
                              hipStream_t stream)
{
  (void)in_sizes; (void)n_in; (void)out_size; (void)ws_size;

  const int* dvl = (const int*)d_in[2];
  const int* evl = (const int*)d_in[3];

  bf16* ws = (bf16*)d_ws;
  // pipeline scratch
  bf16* S0 = ws;                 // also FFN hidden F spans S0..S3 (4*MD)
  bf16* S1 = ws + 1 * MD;
  bf16* S2 = ws + 2 * MD;
  bf16* S4 = ws + 4 * MD;        // Y then Z (in-place LN)
  // converted inputs
  bf16* Xb = ws + 5 * MD;        // X; reused as FFN2 output T3 (X dead by then)
  bf16* Eb = ws + 6 * MD;
  bf16* W  = ws + 7 * MD;
  const bf16 *Wq1 = W,            *Wk1 = W + 262144,  *Wv1 = W + 524288,
             *Wo1 = W + 786432,   *Wq2 = W + 1048576, *Wk2 = W + 1310720,
             *Wv2 = W + 1572864,  *Wo2 = W + 1835008,
             *W1  = W + 2097152,  *b1  = W + 3145728,
             *W2  = W + 3147776,  *b2  = W + 4196352,
             *g1  = W + 4196864,  *be1 = W + 4197376,
             *g2  = W + 4197888,  *be2 = W + 4198400,
             *g3  = W + 4198912,  *be3 = W + 4199424;
  int* flag = (int*)(ws + 62920192);   // = 7*MD + 4199936

  // ---- dtype probe + ingest ----
  probe_dtype<<<dim3(1), dim3(256), 0, stream>>>((const u16*)d_in[0], flag);
  ConvSrc cs;
  cs.p[0] = d_in[0];  cs.p[1] = d_in[1];
  for (int k = 0; k < 12; ++k) cs.p[2 + k] = d_in[4 + k];    // Wq1..b2
  for (int k = 0; k < 6; ++k)  cs.p[14 + k] = d_in[16 + k];  // g1..be3
  convert_all<<<dim3(10248), dim3(256), 0, stream>>>(cs, ws, flag);

  dim3 blk(256);
  dim3 gP(4, 128);    // N=512 GEMMs
  dim3 gF1(16, 128);  // N=2048 GEMM

  // ---- self-attention ----
  gemm_bt<0><<<gP, blk, 0, stream>>>(Xb, Wq1, nullptr, S0, 16384, 512, 512);
  gemm_bt<0><<<gP, blk, 0, stream>>>(Xb, Wk1, nullptr, S1, 16384, 512, 512);
  gemm_bt<0><<<gP, blk, 0, stream>>>(Xb, Wv1, nullptr, S2, 16384, 512, 512);
  flash_attn<<<dim3(2048), blk, 0, stream>>>(S0, S1, S2, S0, dvl, 1);
  gemm_bt<0><<<gP, blk, 0, stream>>>(S0, Wo1, nullptr, S1, 16384, 512, 512);
  add_layernorm<<<dim3(4096), blk, 0, stream>>>(Xb, S1, g1, be1, S4);   // Y

  // ---- cross-attention ----
  gemm_bt<0><<<gP, blk, 0, stream>>>(S4, Wq2, nullptr, S0, 16384, 512, 512);
  gemm_bt<0><<<gP, blk, 0, stream>>>(Eb, Wk2, nullptr, S1, 16384, 512, 512);
  gemm_bt<0><<<gP, blk, 0, stream>>>(Eb, Wv2, nullptr, S2, 16384, 512, 512);
  flash_attn<<<dim3(2048), blk, 0, stream>>>(S0, S1, S2, S0, evl, 0);
  gemm_bt<0><<<gP, blk, 0, stream>>>(S0, Wo2, nullptr, S1, 16384, 512, 512);
  add_layernorm<<<dim3(4096), blk, 0, stream>>>(S4, S1, g2, be2, S4);   // Z

  // ---- FFN ----
  gemm_bt<1><<<gF1, blk, 0, stream>>>(S4, W1, b1, S0, 16384, 2048, 512);   // F -> S0..S3
  gemm_bt<2><<<gP,  blk, 0, stream>>>(S0, W2, b2, Xb, 16384, 512, 2048);   // T3 -> Xb
  add_layernorm_out<<<dim3(4096), blk, 0, stream>>>(S4, Xb, g3, be3, d_out, flag);
}

// Round 4
// 562.056 us; speedup vs baseline: 1.0521x; 1.0521x over previous
//
#include <hip/hip_runtime.h>
#include <cstdint>
#include <cstddef>

typedef __bf16 bf16;
typedef __bf16 bf16x8 __attribute__((ext_vector_type(8)));
typedef float  f32x4  __attribute__((ext_vector_type(4)));
typedef unsigned short u16;

#define NEG_SCORE -1.0e10f
#define MD ((size_t)8388608)   // 16384*512 elements

// ---- async global->LDS 16B copy. LDS dest = wave-uniform base + lane*16 ----
__device__ __forceinline__ void async_copy16(const bf16* gp, bf16* lp) {
  __builtin_amdgcn_global_load_lds(
      (__attribute__((address_space(1))) void*)(gp),
      (__attribute__((address_space(3))) void*)(lp), 16, 0, 0);
}

// =====================================================================
// dtype probe: flag=1 -> inputs are fp32 (measured: they are), 0 -> bf16.
// =====================================================================
__global__ __launch_bounds__(256)
void probe_dtype(const u16* __restrict__ x, int* __restrict__ flag)
{
  __shared__ int bad;
  if (threadIdx.x == 0) bad = 0;
  __syncthreads();
  int my = 0;
  for (int i = threadIdx.x; i < 16384; i += 256) {
    const int e = (x[i] >> 7) & 0xFF;
    if (e >= 141) my = 1;
  }
  if (my) atomicOr(&bad, 1);
  __syncthreads();
  if (threadIdx.x == 0) *flag = bad;
}

// =====================================================================
// Batched conversion of all 20 float tensors into bf16 staging in ws.
// =====================================================================
struct ConvSrc { const void* p[20]; };

__global__ __launch_bounds__(256)
void convert_all(ConvSrc s, bf16* __restrict__ ws, const int* __restrict__ flag)
{
  const int n[20] = {8388608, 8388608,
                     262144, 262144, 262144, 262144, 262144, 262144, 262144, 262144,
                     1048576, 2048, 1048576, 512, 512, 512, 512, 512, 512, 512};
  const unsigned int doff[20] = {
      41943040u, 50331648u,
      58720256u, 58982400u, 59244544u, 59506688u,
      59768832u, 60030976u, 60293120u, 60555264u,
      60817408u, 61865984u, 61868032u, 62916608u,
      62917120u, 62917632u, 62918144u, 62918656u, 62919168u, 62919680u};

  int bi = blockIdx.x;
  int idx = 0, b0 = 0;
  for (; idx < 20; ++idx) {
    const int nb = (n[idx] + 2047) >> 11;
    if (bi < b0 + nb) break;
    b0 += nb;
  }
  const int i = ((bi - b0) << 11) + threadIdx.x * 8;
  if (i >= n[idx]) return;
  bf16* dst = ws + doff[idx] + i;
  if (*flag) {
    const float* sp = (const float*)s.p[idx] + i;
    f32x4 a = *(const f32x4*)sp;
    f32x4 b = *(const f32x4*)(sp + 4);
    bf16x8 o;
#pragma unroll
    for (int e = 0; e < 4; ++e) { o[e] = (bf16)a[e]; o[4 + e] = (bf16)b[e]; }
    *(bf16x8*)dst = o;
  } else {
    *(bf16x8*)dst = *(const bf16x8*)((const bf16*)s.p[idx] + i);
  }
}

// =====================================================================
// GEMM: C[M,N] = act(A[M,K] @ B[N,K]^T + bias), bf16, fp32 accum.
// MODE 0: plain, MODE 1: bias+LeakyReLU(0.01), MODE 2: bias only.
// m97 structure: 128x128 tile, BK=32, async global_load_lds width-16.
// =====================================================================
template<int MODE>
__global__ __launch_bounds__(256)
void gemm_bt(const bf16* __restrict__ A, const bf16* __restrict__ B,
             const bf16* __restrict__ bias, bf16* __restrict__ C,
             int M, int N, int K)
{
  __shared__ __attribute__((aligned(16))) bf16 As[128 * 32];
  __shared__ __attribute__((aligned(16))) bf16 Bs[128 * 32];

  const int t    = threadIdx.x;
  const int wave = t >> 6;
  const int lane = t & 63;
  const int quad = lane >> 4;
  const int l15  = lane & 15;
  const int wr   = (wave >> 1) * 64;
  const int wc   = (wave & 1) * 64;
  const int m0   = blockIdx.y * 128;
  const int n0   = blockIdx.x * 128;

  const f32x4 fz = {0.f, 0.f, 0.f, 0.f};
  f32x4 acc[4][4];
#pragma unroll
  for (int i = 0; i < 4; ++i)
#pragma unroll
    for (int j = 0; j < 4; ++j) acc[i][j] = fz;

  const int nkt = K >> 5;
  for (int kt = 0; kt < nkt; ++kt) {
    const int k0 = kt << 5;
    __syncthreads();   // prior tile's LDS reads done
#pragma unroll
    for (int c = 0; c < 2; ++c) {
      const int s   = c * 256 + t;      // segment 0..511 (8 bf16 each)
      const int row = s >> 2;           // 0..127
      const int kg  = (s & 3) << 3;     // 0,8,16,24
      async_copy16(A + (size_t)(m0 + row) * K + k0 + kg,
                   As + ((c * 256 + wave * 64) << 3));
      async_copy16(B + (size_t)(n0 + row) * K + k0 + kg,
                   Bs + ((c * 256 + wave * 64) << 3));
    }
    __syncthreads();   // drains vmcnt(0): staged data visible

    bf16x8 af[4], bfv[4];
#pragma unroll
    for (int i = 0; i < 4; ++i)
      af[i] = *(const bf16x8*)(As + (wr + i * 16 + l15) * 32 + quad * 8);
#pragma unroll
    for (int j = 0; j < 4; ++j)
      bfv[j] = *(const bf16x8*)(Bs + (wc + j * 16 + l15) * 32 + quad * 8);
#pragma unroll
    for (int i = 0; i < 4; ++i)
#pragma unroll
      for (int j = 0; j < 4; ++j)
        acc[i][j] = __builtin_amdgcn_mfma_f32_16x16x32_bf16(af[i], bfv[j],
                                                            acc[i][j], 0, 0, 0);
  }

#pragma unroll
  for (int i = 0; i < 4; ++i) {
    const int m = m0 + wr + i * 16 + quad * 4;
#pragma unroll
    for (int j = 0; j < 4; ++j) {
      const int n = n0 + wc + j * 16 + l15;
      float bv = 0.f;
      if (MODE >= 1) bv = (float)bias[n];
#pragma unroll
      for (int r = 0; r < 4; ++r) {
        float v = acc[i][j][r];
        if (MODE >= 1) v += bv;
        if (MODE == 1) v = v > 0.f ? v : 0.01f * v;
        C[(size_t)(m + r) * N + n] = (bf16)v;
      }
    }
  }
}

// =====================================================================
// Flash attention v2. One block = (b, h, 128 queries); 4 waves x 32 q.
// Q fragments loaded global->registers (no Q LDS). K tile: coalesced
// b128 stage. V^T tile: lane->d row loads (128B coalesced) + b128 stores
// (conflict-free). Strided Q/KV supported (fused projection buffers).
// =====================================================================
__global__ __launch_bounds__(256)
void flash_attn(const bf16* __restrict__ Qp, const bf16* __restrict__ Kp,
                const bf16* __restrict__ Vp, bf16* __restrict__ Op,
                const int* __restrict__ vlen, int per_query, int sq, int skv)
{
  __shared__ __attribute__((aligned(16))) bf16 Ks[64][72];
  __shared__ __attribute__((aligned(16))) bf16 VsT[64][72];   // [d][k]
  __shared__ __attribute__((aligned(16))) bf16 Ps[4][32][72]; // per-wave [q][k]
  __shared__ int vlmax_sh;

  const int t    = threadIdx.x;
  const int wave = t >> 6;
  const int lane = t & 63;
  const int quad = lane >> 4;
  const int l15  = lane & 15;
  const int bx   = blockIdx.x;
  const int qt   = bx & 3;
  const int h    = (bx >> 2) & 7;
  const int b    = bx >> 5;
  const int q0   = qt * 128 + wave * 32;   // wave's first q row

  // Q fragments: A[m=l15][k=quad*8+j], 2 m-tiles x 2 k-steps
  bf16x8 qfrag[2][2];
#pragma unroll
  for (int mt = 0; mt < 2; ++mt)
#pragma unroll
    for (int ks = 0; ks < 2; ++ks)
      qfrag[mt][ks] = *(const bf16x8*)(Qp +
          (size_t)(b * 512 + q0 + mt * 16 + l15) * sq + h * 64 + ks * 32 + quad * 8);

  int vl_r[2][4];
  int myvl = 1;
#pragma unroll
  for (int mt = 0; mt < 2; ++mt)
#pragma unroll
    for (int r = 0; r < 4; ++r) {
      const int q = q0 + mt * 16 + quad * 4 + r;
      const int v = per_query ? vlen[b * 512 + q] : vlen[b];
      vl_r[mt][r] = v;
      myvl = v > myvl ? v : myvl;
    }

  if (t == 0) vlmax_sh = 1;
  __syncthreads();
  // wave-reduce then one atomic per wave
#pragma unroll
  for (int off = 1; off < 64; off <<= 1) {
    const int o = __shfl_xor(myvl, off);
    myvl = o > myvl ? o : myvl;
  }
  if (lane == 0) atomicMax(&vlmax_sh, myvl);
  __syncthreads();
  const int ktiles = (vlmax_sh + 63) >> 6;

  const f32x4 fz = {0.f, 0.f, 0.f, 0.f};
  float m_run[2][4], l_run[2][4];
  f32x4 o_acc[2][4];
#pragma unroll
  for (int mt = 0; mt < 2; ++mt)
#pragma unroll
    for (int r = 0; r < 4; ++r) { m_run[mt][r] = -1e30f; l_run[mt][r] = 0.f; }
#pragma unroll
  for (int mt = 0; mt < 2; ++mt)
#pragma unroll
    for (int nt = 0; nt < 4; ++nt) o_acc[mt][nt] = fz;

  for (int kt = 0; kt < ktiles; ++kt) {
    const int k0 = kt * 64;
    __syncthreads();   // prior tile fully consumed
    // ---- stage K tile (coalesced b128, rows t>>3 and +32) ----
    {
      const int r0 = t >> 3;
      const int c0 = (t & 7) * 8;
      const bf16* g = Kp + (size_t)(b * 512 + k0 + r0) * skv + h * 64 + c0;
      *(bf16x8*)&Ks[r0][c0]      = *(const bf16x8*)g;
      *(bf16x8*)&Ks[r0 + 32][c0] = *(const bf16x8*)(g + (size_t)32 * skv);
    }
    // ---- stage V^T: lane->d; wave w covers k in [w*16, w*16+16) ----
    {
      const bf16* g = Vp + (size_t)(b * 512 + k0 + wave * 16) * skv + h * 64 + lane;
      bf16x8 lo, hi;
#pragma unroll
      for (int kk = 0; kk < 8; ++kk) lo[kk] = g[(size_t)kk * skv];
#pragma unroll
      for (int kk = 0; kk < 8; ++kk) hi[kk] = g[(size_t)(kk + 8) * skv];
      *(bf16x8*)&VsT[lane][wave * 16]     = lo;
      *(bf16x8*)&VsT[lane][wave * 16 + 8] = hi;
    }
    __syncthreads();

    // ---- QK^T: S[2 mt][4 nt], contraction over d=64 ----
    bf16x8 bk[2][4];
#pragma unroll
    for (int ks = 0; ks < 2; ++ks)
#pragma unroll
      for (int nt = 0; nt < 4; ++nt)
        bk[ks][nt] = *(const bf16x8*)&Ks[nt * 16 + l15][ks * 32 + quad * 8];
    f32x4 s[2][4];
#pragma unroll
    for (int mt = 0; mt < 2; ++mt)
#pragma unroll
      for (int nt = 0; nt < 4; ++nt) s[mt][nt] = fz;
#pragma unroll
    for (int mt = 0; mt < 2; ++mt)
#pragma unroll
      for (int ks = 0; ks < 2; ++ks)
#pragma unroll
        for (int nt = 0; nt < 4; ++nt)
          s[mt][nt] = __builtin_amdgcn_mfma_f32_16x16x32_bf16(
              qfrag[mt][ks], bk[ks][nt], s[mt][nt], 0, 0, 0);

    // ---- scale + mask ----
    float sv[2][4][4];
#pragma unroll
    for (int mt = 0; mt < 2; ++mt)
#pragma unroll
      for (int nt = 0; nt < 4; ++nt) {
        const int k_abs = k0 + nt * 16 + l15;
#pragma unroll
        for (int r = 0; r < 4; ++r) {
          const float v = s[mt][nt][r] * 0.125f;
          sv[mt][nt][r] = (k_abs < vl_r[mt][r]) ? v : NEG_SCORE;
        }
      }

    // ---- online softmax (row stats across 16 lanes of a quad-row) ----
    float alpha[2][4];
#pragma unroll
    for (int mt = 0; mt < 2; ++mt)
#pragma unroll
      for (int r = 0; r < 4; ++r) {
        float v = fmaxf(fmaxf(sv[mt][0][r], sv[mt][1][r]),
                        fmaxf(sv[mt][2][r], sv[mt][3][r]));
#pragma unroll
        for (int off = 1; off < 16; off <<= 1)
          v = fmaxf(v, __shfl_xor(v, off));
        const float m_new = fmaxf(m_run[mt][r], v);
        alpha[mt][r] = __expf(m_run[mt][r] - m_new);
        m_run[mt][r] = m_new;
      }
#pragma unroll
    for (int mt = 0; mt < 2; ++mt)
#pragma unroll
      for (int r = 0; r < 4; ++r) {
        float sum = 0.f;
#pragma unroll
        for (int nt = 0; nt < 4; ++nt) {
          const float p = __expf(sv[mt][nt][r] - m_run[mt][r]);
          sv[mt][nt][r] = p;
          sum += p;
        }
#pragma unroll
        for (int off = 1; off < 16; off <<= 1)
          sum += __shfl_xor(sum, off);
        l_run[mt][r] = alpha[mt][r] * l_run[mt][r] + sum;
      }

    // ---- P -> LDS (C-layout scatter), rescale O ----
#pragma unroll
    for (int mt = 0; mt < 2; ++mt)
#pragma unroll
      for (int nt = 0; nt < 4; ++nt) {
#pragma unroll
        for (int r = 0; r < 4; ++r)
          Ps[wave][mt * 16 + quad * 4 + r][nt * 16 + l15] = (bf16)sv[mt][nt][r];
        o_acc[mt][nt][0] *= alpha[mt][0];
        o_acc[mt][nt][1] *= alpha[mt][1];
        o_acc[mt][nt][2] *= alpha[mt][2];
        o_acc[mt][nt][3] *= alpha[mt][3];
      }
    __syncthreads();   // Ps visible before b128 reads

    // ---- O += P @ V ----
    bf16x8 bv[2][4], ap[2][2];
#pragma unroll
    for (int ks = 0; ks < 2; ++ks)
#pragma unroll
      for (int nt = 0; nt < 4; ++nt)
        bv[ks][nt] = *(const bf16x8*)&VsT[nt * 16 + l15][ks * 32 + quad * 8];
#pragma unroll
    for (int mt = 0; mt < 2; ++mt)
#pragma unroll
      for (int ks = 0; ks < 2; ++ks)
        ap[mt][ks] = *(const bf16x8*)&Ps[wave][mt * 16 + l15][ks * 32 + quad * 8];
#pragma unroll
    for (int mt = 0; mt < 2; ++mt)
#pragma unroll
      for (int ks = 0; ks < 2; ++ks)
#pragma unroll
        for (int nt = 0; nt < 4; ++nt)
          o_acc[mt][nt] = __builtin_amdgcn_mfma_f32_16x16x32_bf16(
              ap[mt][ks], bv[ks][nt], o_acc[mt][nt], 0, 0, 0);
  }

  // ---- epilogue ----
#pragma unroll
  for (int mt = 0; mt < 2; ++mt)
#pragma unroll
    for (int r = 0; r < 4; ++r) {
      const int q = q0 + mt * 16 + quad * 4 + r;
      const float inv_l = (l_run[mt][r] > 0.f) ? (1.f / l_run[mt][r]) : 0.f;
#pragma unroll
      for (int nt = 0; nt < 4; ++nt)
        Op[(size_t)(b * 512 + q) * 512 + h * 64 + nt * 16 + l15] =
            (bf16)(o_acc[mt][nt][r] * inv_l);
    }
}

// =====================================================================
// AddNorm (internal, bf16 out). One wave per 512-row. In-place safe.
// =====================================================================
__global__ __launch_bounds__(256)
void add_layernorm(const bf16* X, const bf16* R,
                   const bf16* __restrict__ gamma, const bf16* __restrict__ beta,
                   bf16* Out)
{
  const int t    = threadIdx.x;
  const int wave = t >> 6;
  const int lane = t & 63;
  const size_t row  = (size_t)blockIdx.x * 4 + wave;
  const size_t base = row * 512 + lane * 8;

  bf16x8 xv = *(const bf16x8*)(X + base);
  bf16x8 rv = *(const bf16x8*)(R + base);
  float v[8];
  float sum = 0.f, ss = 0.f;
#pragma unroll
  for (int i = 0; i < 8; ++i) {
    v[i] = (float)xv[i] + (float)rv[i];
    sum += v[i];
    ss  += v[i] * v[i];
  }
#pragma unroll
  for (int off = 1; off < 64; off <<= 1) {
    sum += __shfl_xor(sum, off);
    ss  += __shfl_xor(ss, off);
  }
  const float mean = sum * (1.f / 512.f);
  const float var  = ss * (1.f / 512.f) - mean * mean;
  const float rstd = rsqrtf(var + 1e-5f);

  bf16x8 gv = *(const bf16x8*)(gamma + lane * 8);
  bf16x8 bv = *(const bf16x8*)(beta + lane * 8);
  bf16x8 ov;
#pragma unroll
  for (int i = 0; i < 8; ++i)
    ov[i] = (bf16)(((v[i] - mean) * rstd) * (float)gv[i] + (float)bv[i]);
  *(bf16x8*)(Out + base) = ov;
}

// =====================================================================
// Final AddNorm: writes d_out as fp32 or bf16 per the dtype flag.
// =====================================================================
__global__ __launch_bounds__(256)
void add_layernorm_out(const bf16* X, const bf16* R,
                       const bf16* __restrict__ gamma, const bf16* __restrict__ beta,
                       void* Out, const int* __restrict__ flag)
{
  const int t    = threadIdx.x;
  const int wave = t >> 6;
  const int lane = t & 63;
  const size_t row  = (size_t)blockIdx.x * 4 + wave;
  const size_t base = row * 512 + lane * 8;

  bf16x8 xv = *(const bf16x8*)(X + base);
  bf16x8 rv = *(const bf16x8*)(R + base);
  float v[8];
  float sum = 0.f, ss = 0.f;
#pragma unroll
  for (int i = 0; i < 8; ++i) {
    v[i] = (float)xv[i] + (float)rv[i];
    sum += v[i];
    ss  += v[i] * v[i];
  }
#pragma unroll
  for (int off = 1; off < 64; off <<= 1) {
    sum += __shfl_xor(sum, off);
    ss  += __shfl_xor(ss, off);
  }
  const float mean = sum * (1.f / 512.f);
  const float var  = ss * (1.f / 512.f) - mean * mean;
  const float rstd = rsqrtf(var + 1e-5f);

  bf16x8 gv = *(const bf16x8*)(gamma + lane * 8);
  bf16x8 bv = *(const bf16x8*)(beta + lane * 8);
  float o[8];
#pragma unroll
  for (int i = 0; i < 8; ++i)
    o[i] = ((v[i] - mean) * rstd) * (float)gv[i] + (float)bv[i];

  if (*flag) {
    float* op = (float*)Out + base;
    f32x4 o0 = {o[0], o[1], o[2], o[3]};
    f32x4 o1 = {o[4], o[5], o[6], o[7]};
    *(f32x4*)op       = o0;
    *(f32x4*)(op + 4) = o1;
  } else {
    bf16x8 ov;
#pragma unroll
    for (int i = 0; i < 8; ++i) ov[i] = (bf16)o[i];
    *(bf16x8*)((bf16*)Out + base) = ov;
  }
}

// =====================================================================
extern "C" void kernel_launch(void* const* d_in, const int* in_sizes, int n_in,
                              void* d_out, int out_size, void* d_ws, size_t ws_size,
                              hipStream_t stream)
{
  (void)in_sizes; (void)n_in; (void)out_size; (void)ws_size;

  const int* dvl = (const int*)d_in[2];
  const int* evl = (const int*)d_in[3];

  bf16* ws = (bf16*)d_ws;
  bf16* S0 = ws;                 // QKV packed / FFN hidden (S0..S3)
  bf16* S1 = ws + 1 * MD;
  bf16* S3 = ws + 3 * MD;        // attention output O
  bf16* S4 = ws + 4 * MD;        // Y then Z (in-place LN)
  bf16* Xb = ws + 5 * MD;        // X bf16; reused as FFN2 output
  bf16* Eb = ws + 6 * MD;
  bf16* W  = ws + 7 * MD;
  const bf16 *Wq1 = W,            /* Wk1,Wv1 contiguous after Wq1 */
             *Wo1 = W + 786432,   *Wq2 = W + 1048576, *Wk2 = W + 1310720,
             /* Wv2 contiguous after Wk2 */
             *Wo2 = W + 1835008,
             *W1  = W + 2097152,  *b1  = W + 3145728,
             *W2  = W + 3147776,  *b2  = W + 4196352,
             *g1  = W + 4196864,  *be1 = W + 4197376,
             *g2  = W + 4197888,  *be2 = W + 4198400,
             *g3  = W + 4198912,  *be3 = W + 4199424;
  int* flag = (int*)(ws + 62920192);

  // ---- dtype probe + ingest ----
  probe_dtype<<<dim3(1), dim3(256), 0, stream>>>((const u16*)d_in[0], flag);
  ConvSrc cs;
  cs.p[0] = d_in[0];  cs.p[1] = d_in[1];
  for (int k = 0; k < 12; ++k) cs.p[2 + k] = d_in[4 + k];
  for (int k = 0; k < 6; ++k)  cs.p[14 + k] = d_in[16 + k];
  convert_all<<<dim3(10248), dim3(256), 0, stream>>>(cs, ws, flag);

  dim3 blk(256);
  dim3 gP(4, 128);     // N=512
  dim3 gQKV(12, 128);  // N=1536
  dim3 gKV(8, 128);    // N=1024
  dim3 gF1(16, 128);   // N=2048

  // ---- self-attention ----
  gemm_bt<0><<<gQKV, blk, 0, stream>>>(Xb, Wq1, nullptr, S0, 16384, 1536, 512);
  flash_attn<<<dim3(1024), blk, 0, stream>>>(S0, S0 + 512, S0 + 1024, S3, dvl, 1, 1536, 1536);
  gemm_bt<0><<<gP, blk, 0, stream>>>(S3, Wo1, nullptr, S1, 16384, 512, 512);
  add_layernorm<<<dim3(4096), blk, 0, stream>>>(Xb, S1, g1, be1, S4);   // Y

  // ---- cross-attention ----
  gemm_bt<0><<<gP,  blk, 0, stream>>>(S4, Wq2, nullptr, S0, 16384, 512, 512);
  gemm_bt<0><<<gKV, blk, 0, stream>>>(Eb, Wk2, nullptr, S1, 16384, 1024, 512);
  flash_attn<<<dim3(1024), blk, 0, stream>>>(S0, S1, S1 + 512, S3, evl, 0, 512, 1024);
  gemm_bt<0><<<gP, blk, 0, stream>>>(S3, Wo2, nullptr, S1, 16384, 512, 512);
  add_layernorm<<<dim3(4096), blk, 0, stream>>>(S4, S1, g2, be2, S4);   // Z

  // ---- FFN ----
  gemm_bt<1><<<gF1, blk, 0, stream>>>(S4, W1, b1, S0, 16384, 2048, 512);
  gemm_bt<2><<<gP,  blk, 0, stream>>>(S0, W2, b2, Xb, 16384, 512, 2048);
  add_layernorm_out<<<dim3(4096), blk, 0, stream>>>(S4, Xb, g3, be3, d_out, flag);
}